// Round 1
// baseline (164.108 us; speedup 1.0000x reference)
//
#include <hip/hip_runtime.h>
#include <hip/hip_bf16.h>
#include <stdint.h>

#define NNODES 4096
#define MASKW  (NNODES / 32)   // 128 uint32 words per adjacency row
#define IN_F   512
#define HID    64
#define OUTF   16
#define MAXNBR 1024

// ---------------- edge scatter: build symmetric adjacency bitmask ----------------
__global__ void scatter_edges(const int* __restrict__ ei, int E, uint32_t* __restrict__ mask) {
    int e = blockIdx.x * blockDim.x + threadIdx.x;
    if (e >= E) return;
    int u = ei[e], v = ei[E + e];
    if ((unsigned)u < NNODES && (unsigned)v < NNODES) {
        atomicOr(&mask[(size_t)u * MASKW + (v >> 5)], 1u << (v & 31));
        atomicOr(&mask[(size_t)v * MASKW + (u >> 5)], 1u << (u & 31));
    }
}

// ---------------- layer 1 GEMM: h1 = x @ W1, fused es/ed projections ----------------
// block = 64 threads, 8 rows (nodes) per block
__global__ void __launch_bounds__(64) gemm1(const float* __restrict__ x, const float* __restrict__ W1,
                      const float* __restrict__ a_src, const float* __restrict__ a_dst,
                      float* __restrict__ h1, float* __restrict__ es, float* __restrict__ ed) {
    __shared__ float xs[8][IN_F];
    __shared__ float hs[8][HID];
    int f = threadIdx.x;            // 0..63 = output feature
    int i0 = blockIdx.x * 8;
    // stage 8 rows of x
    for (int t = f; t < 8 * IN_F; t += 64) {
        int r = t >> 9, k = t & (IN_F - 1);
        xs[r][k] = x[(size_t)(i0 + r) * IN_F + k];
    }
    __syncthreads();
    float acc[8];
#pragma unroll
    for (int r = 0; r < 8; ++r) acc[r] = 0.f;
    for (int k = 0; k < IN_F; ++k) {
        float w = W1[k * HID + f];
#pragma unroll
        for (int r = 0; r < 8; ++r) acc[r] += xs[r][k] * w;
    }
#pragma unroll
    for (int r = 0; r < 8; ++r) {
        hs[r][f] = acc[r];
        h1[(size_t)(i0 + r) * HID + f] = acc[r];
    }
    __syncthreads();
    // es/ed: thread t handles (row r = t>>3, head h = t&7); F1 = 8
    int r = f >> 3, h = f & 7;
    float s1 = 0.f, s2 = 0.f;
#pragma unroll
    for (int ff = 0; ff < 8; ++ff) {
        float hv = hs[r][h * 8 + ff];
        s1 += hv * a_src[h * 8 + ff];
        s2 += hv * a_dst[h * 8 + ff];
    }
    es[h * NNODES + (i0 + r)] = s1;
    ed[h * NNODES + (i0 + r)] = s2;
}

// ---------------- layer 1 attention: 1 block per node, 8 waves = 8 heads ----------------
__global__ void __launch_bounds__(512) attn1(const uint32_t* __restrict__ mask,
    const float* __restrict__ h1, const float* __restrict__ es, const float* __restrict__ ed,
    float* __restrict__ hout) {
    __shared__ int nbr[MAXNBR];
    __shared__ int cnt;
    int i = blockIdx.x;
    int tid = threadIdx.x;
    if (tid == 0) cnt = 0;
    __syncthreads();
    // gather neighbor list from bitmask row (shared by all 8 heads)
    for (int w = tid; w < MASKW; w += 512) {
        uint32_t bits = mask[(size_t)i * MASKW + w];
        while (bits) {
            int b = __ffs(bits) - 1;
            bits &= bits - 1;
            int pos = atomicAdd(&cnt, 1);
            if (pos < MAXNBR) nbr[pos] = w * 32 + b;
        }
    }
    __syncthreads();
    int n = cnt < MAXNBR ? cnt : MAXNBR;
    int h = tid >> 6, lane = tid & 63;
    float es_i = es[h * NNODES + i];
    const float* edh = ed + h * NNODES;
    float m = -1e30f, s = 0.f;
    float acc[8];
#pragma unroll
    for (int f = 0; f < 8; ++f) acc[f] = 0.f;
    for (int t = lane; t < n; t += 64) {
        int j = nbr[t];
        float v = es_i + edh[j];
        v = v > 0.f ? v : 0.2f * v;          // leaky_relu slope 0.2
        float nm = fmaxf(m, v);
        float sc = __expf(m - nm);
        float p  = __expf(v - nm);
        s = s * sc + p;
        const float* hj = h1 + (size_t)j * HID + h * 8;
#pragma unroll
        for (int f = 0; f < 8; ++f) acc[f] = acc[f] * sc + p * hj[f];
        m = nm;
    }
    // butterfly merge of (m, s, acc[8]) across the 64-lane wave
#pragma unroll
    for (int off = 32; off >= 1; off >>= 1) {
        float mo = __shfl_xor(m, off, 64);
        float so = __shfl_xor(s, off, 64);
        float ao[8];
#pragma unroll
        for (int f = 0; f < 8; ++f) ao[f] = __shfl_xor(acc[f], off, 64);
        float nm = fmaxf(m, mo);
        float c1 = __expf(m - nm), c2 = __expf(mo - nm);
        s = s * c1 + so * c2;
#pragma unroll
        for (int f = 0; f < 8; ++f) acc[f] = acc[f] * c1 + ao[f] * c2;
        m = nm;
    }
    if (lane == 0) {
        float inv = (s > 0.f) ? 1.f / s : 0.f;
#pragma unroll
        for (int f = 0; f < 8; ++f) {
            float o = acc[f] * inv;
            o = o > 0.f ? o : (__expf(o) - 1.f);   // ELU fused
            hout[(size_t)i * HID + h * 8 + f] = o;
        }
    }
}

// ---------------- layer 2 GEMM: h2 = hout @ W2, fused es2/ed2 ----------------
// block = 64 threads, 4 rows per block (16 out features each)
__global__ void __launch_bounds__(64) gemm2(const float* __restrict__ hin, const float* __restrict__ W2,
                      const float* __restrict__ a_src, const float* __restrict__ a_dst,
                      float* __restrict__ h2, float* __restrict__ es, float* __restrict__ ed) {
    __shared__ float hs[4][HID];
    __shared__ float os[4][OUTF];
    int tid = threadIdx.x;          // 0..63
    int i0 = blockIdx.x * 4;
    for (int t = tid; t < 4 * HID; t += 64)
        hs[t >> 6][t & 63] = hin[(size_t)i0 * HID + t];
    __syncthreads();
    int r = tid >> 4, f = tid & 15;
    float acc = 0.f;
#pragma unroll
    for (int k = 0; k < HID; ++k) acc += hs[r][k] * W2[k * OUTF + f];
    os[r][f] = acc;
    h2[(size_t)(i0 + r) * OUTF + f] = acc;
    __syncthreads();
    if (tid < 4) {
        float s1 = 0.f, s2 = 0.f;
#pragma unroll
        for (int ff = 0; ff < OUTF; ++ff) {
            s1 += os[tid][ff] * a_src[ff];
            s2 += os[tid][ff] * a_dst[ff];
        }
        es[i0 + tid] = s1;
        ed[i0 + tid] = s2;
    }
}

// ---------------- layer 2 attention + mean(1 head) + log_softmax ----------------
__global__ void __launch_bounds__(64) attn2(const uint32_t* __restrict__ mask,
    const float* __restrict__ h2, const float* __restrict__ es, const float* __restrict__ ed,
    float* __restrict__ out) {
    __shared__ int nbr[MAXNBR];
    __shared__ int cnt;
    int i = blockIdx.x;
    int lane = threadIdx.x;
    if (lane == 0) cnt = 0;
    __syncthreads();
    for (int w = lane; w < MASKW; w += 64) {
        uint32_t bits = mask[(size_t)i * MASKW + w];
        while (bits) {
            int b = __ffs(bits) - 1;
            bits &= bits - 1;
            int pos = atomicAdd(&cnt, 1);
            if (pos < MAXNBR) nbr[pos] = w * 32 + b;
        }
    }
    __syncthreads();
    int n = cnt < MAXNBR ? cnt : MAXNBR;
    float es_i = es[i];
    float m = -1e30f, s = 0.f;
    float acc[OUTF];
#pragma unroll
    for (int f = 0; f < OUTF; ++f) acc[f] = 0.f;
    for (int t = lane; t < n; t += 64) {
        int j = nbr[t];
        float v = es_i + ed[j];
        v = v > 0.f ? v : 0.2f * v;
        float nm = fmaxf(m, v);
        float sc = __expf(m - nm);
        float p  = __expf(v - nm);
        s = s * sc + p;
        const float* hj = h2 + (size_t)j * OUTF;
#pragma unroll
        for (int f = 0; f < OUTF; ++f) acc[f] = acc[f] * sc + p * hj[f];
        m = nm;
    }
#pragma unroll
    for (int off = 32; off >= 1; off >>= 1) {
        float mo = __shfl_xor(m, off, 64);
        float so = __shfl_xor(s, off, 64);
        float ao[OUTF];
#pragma unroll
        for (int f = 0; f < OUTF; ++f) ao[f] = __shfl_xor(acc[f], off, 64);
        float nm = fmaxf(m, mo);
        float c1 = __expf(m - nm), c2 = __expf(mo - nm);
        s = s * c1 + so * c2;
#pragma unroll
        for (int f = 0; f < OUTF; ++f) acc[f] = acc[f] * c1 + ao[f] * c2;
        m = nm;
    }
    if (lane == 0) {
        float inv = (s > 0.f) ? 1.f / s : 0.f;
        float v[OUTF];
        float mx = -1e30f;
#pragma unroll
        for (int f = 0; f < OUTF; ++f) {
            v[f] = acc[f] * inv;
            mx = fmaxf(mx, v[f]);
        }
        float se = 0.f;
#pragma unroll
        for (int f = 0; f < OUTF; ++f) se += __expf(v[f] - mx);
        float lse = mx + __logf(se);
#pragma unroll
        for (int f = 0; f < OUTF; ++f)
            out[(size_t)i * OUTF + f] = v[f] - lse;
    }
}

extern "C" void kernel_launch(void* const* d_in, const int* in_sizes, int n_in,
                              void* d_out, int out_size, void* d_ws, size_t ws_size,
                              hipStream_t stream) {
    const float* x   = (const float*)d_in[0];
    const int*   ei  = (const int*)d_in[1];
    const float* W1  = (const float*)d_in[2];
    const float* a1s = (const float*)d_in[3];
    const float* a1d = (const float*)d_in[4];
    const float* W2  = (const float*)d_in[5];
    const float* a2s = (const float*)d_in[6];
    const float* a2d = (const float*)d_in[7];
    float* out = (float*)d_out;
    int E = in_sizes[1] / 2;

    char* ws = (char*)d_ws;
    uint32_t* mask = (uint32_t*)ws;                // 2 MiB
    float* h1   = (float*)(ws + 2097152);          // 1 MiB   [N][64]
    float* es1  = (float*)(ws + 3145728);          // 128 KiB [8][N]
    float* ed1  = (float*)(ws + 3276800);          // 128 KiB [8][N]
    float* hout = (float*)(ws + 3407872);          // 1 MiB   [N][64]
    float* h2   = (float*)(ws + 4456448);          // 256 KiB [N][16]
    float* es2  = (float*)(ws + 4718592);          // 16 KiB  [N]
    float* ed2  = (float*)(ws + 4734976);          // 16 KiB  [N]

    hipMemsetAsync(mask, 0, NNODES * MASKW * sizeof(uint32_t), stream);
    scatter_edges<<<(E + 255) / 256, 256, 0, stream>>>(ei, E, mask);
    gemm1<<<NNODES / 8, 64, 0, stream>>>(x, W1, a1s, a1d, h1, es1, ed1);
    attn1<<<NNODES, 512, 0, stream>>>(mask, h1, es1, ed1, hout);
    gemm2<<<NNODES / 4, 64, 0, stream>>>(hout, W2, a2s, a2d, h2, es2, ed2);
    attn2<<<NNODES, 64, 0, stream>>>(mask, h2, es2, ed2, out);
}

// Round 2
// 134.140 us; speedup vs baseline: 1.2234x; 1.2234x over previous
//
#include <hip/hip_runtime.h>
#include <hip/hip_bf16.h>
#include <stdint.h>

#define NNODES 4096
#define MASKW  (NNODES / 32)   // 128 uint32 words per adjacency row
#define IN_F   512
#define HID    64
#define OUTF   16
#define MAXNBR 1024

// ---------------- edge scatter: build symmetric adjacency bitmask ----------------
__global__ void scatter_edges(const int* __restrict__ ei, int E, uint32_t* __restrict__ mask) {
    int e = blockIdx.x * blockDim.x + threadIdx.x;
    if (e >= E) return;
    int u = ei[e], v = ei[E + e];
    if ((unsigned)u < NNODES && (unsigned)v < NNODES) {
        atomicOr(&mask[(size_t)u * MASKW + (v >> 5)], 1u << (v & 31));
        atomicOr(&mask[(size_t)v * MASKW + (u >> 5)], 1u << (u & 31));
    }
}

// ---------------- layer 1 GEMM: h1 = x @ W1, fused es/ed projections ----------------
// block = 512 threads = 8 waves; 8 rows per block; split-K: wave w owns k in [w*64, w*64+64)
__global__ void __launch_bounds__(512) gemm1(const float* __restrict__ x, const float* __restrict__ W1,
                      const float* __restrict__ a_src, const float* __restrict__ a_dst,
                      float* __restrict__ h1, float* __restrict__ es, float* __restrict__ ed) {
    __shared__ float xs[8][IN_F];        // 16 KB (reused as hs[8][64] after compute)
    __shared__ float part[8][8][HID];    // 16 KB  [wave][row][feat]
    int tid = threadIdx.x;
    int w = tid >> 6, f = tid & 63;
    int i0 = blockIdx.x * 8;

    // stage 8 rows of x with float4 (1024 float4 over 512 threads)
    const float4* xv = (const float4*)(x + (size_t)i0 * IN_F);
    float4* xsv = (float4*)&xs[0][0];
    xsv[tid] = xv[tid];
    xsv[tid + 512] = xv[tid + 512];
    __syncthreads();

    float acc[8];
#pragma unroll
    for (int r = 0; r < 8; ++r) acc[r] = 0.f;
    int k0 = w * 64;
    for (int k = k0; k < k0 + 64; k += 4) {
        float w0 = W1[(k + 0) * HID + f];
        float w1_ = W1[(k + 1) * HID + f];
        float w2 = W1[(k + 2) * HID + f];
        float w3 = W1[(k + 3) * HID + f];
#pragma unroll
        for (int r = 0; r < 8; ++r) {
            float4 xr = *(const float4*)&xs[r][k];   // broadcast ds_read_b128
            acc[r] += xr.x * w0 + xr.y * w1_ + xr.z * w2 + xr.w * w3;
        }
    }
#pragma unroll
    for (int r = 0; r < 8; ++r) part[w][r][f] = acc[r];
    __syncthreads();

    // reduce the 8 K-slices: 512 outputs, one per thread
    {
        int r = tid >> 6, ff = tid & 63;
        float v = 0.f;
#pragma unroll
        for (int p = 0; p < 8; ++p) v += part[p][r][ff];
        h1[(size_t)(i0 + r) * HID + ff] = v;
        xs[r][ff] = v;                   // reuse xs as hs
    }
    __syncthreads();

    // es/ed: thread t<64 handles (row r = t>>3, head h = t&7); F1 = 8
    if (tid < 64) {
        int r = tid >> 3, h = tid & 7;
        float s1 = 0.f, s2 = 0.f;
#pragma unroll
        for (int ff = 0; ff < 8; ++ff) {
            float hv = xs[r][h * 8 + ff];
            s1 += hv * a_src[h * 8 + ff];
            s2 += hv * a_dst[h * 8 + ff];
        }
        es[h * NNODES + (i0 + r)] = s1;
        ed[h * NNODES + (i0 + r)] = s2;
    }
}

// ---------------- layer 1 attention: 1 block per node, 8 waves = 8 heads ----------------
__global__ void __launch_bounds__(512) attn1(const uint32_t* __restrict__ mask,
    const float* __restrict__ h1, const float* __restrict__ es, const float* __restrict__ ed,
    float* __restrict__ hout) {
    __shared__ int nbr[MAXNBR];
    __shared__ int cnt;
    int i = blockIdx.x;
    int tid = threadIdx.x;
    if (tid == 0) cnt = 0;
    __syncthreads();
    // gather neighbor list from bitmask row (shared by all 8 heads)
    for (int w = tid; w < MASKW; w += 512) {
        uint32_t bits = mask[(size_t)i * MASKW + w];
        while (bits) {
            int b = __ffs(bits) - 1;
            bits &= bits - 1;
            int pos = atomicAdd(&cnt, 1);
            if (pos < MAXNBR) nbr[pos] = w * 32 + b;
        }
    }
    __syncthreads();
    int n = cnt < MAXNBR ? cnt : MAXNBR;
    int h = tid >> 6, lane = tid & 63;
    float es_i = es[h * NNODES + i];
    const float* edh = ed + h * NNODES;
    float m = -1e30f, s = 0.f;
    float acc[8];
#pragma unroll
    for (int f = 0; f < 8; ++f) acc[f] = 0.f;
    for (int t = lane; t < n; t += 64) {
        int j = nbr[t];
        float v = es_i + edh[j];
        v = v > 0.f ? v : 0.2f * v;          // leaky_relu slope 0.2
        float nm = fmaxf(m, v);
        float sc = __expf(m - nm);
        float p  = __expf(v - nm);
        s = s * sc + p;
        const float* hj = h1 + (size_t)j * HID + h * 8;
#pragma unroll
        for (int f = 0; f < 8; ++f) acc[f] = acc[f] * sc + p * hj[f];
        m = nm;
    }
    // butterfly merge of (m, s, acc[8]) across the 64-lane wave
#pragma unroll
    for (int off = 32; off >= 1; off >>= 1) {
        float mo = __shfl_xor(m, off, 64);
        float so = __shfl_xor(s, off, 64);
        float ao[8];
#pragma unroll
        for (int f = 0; f < 8; ++f) ao[f] = __shfl_xor(acc[f], off, 64);
        float nm = fmaxf(m, mo);
        float c1 = __expf(m - nm), c2 = __expf(mo - nm);
        s = s * c1 + so * c2;
#pragma unroll
        for (int f = 0; f < 8; ++f) acc[f] = acc[f] * c1 + ao[f] * c2;
        m = nm;
    }
    if (lane == 0) {
        float inv = (s > 0.f) ? 1.f / s : 0.f;
#pragma unroll
        for (int f = 0; f < 8; ++f) {
            float o = acc[f] * inv;
            o = o > 0.f ? o : (__expf(o) - 1.f);   // ELU fused
            hout[(size_t)i * HID + h * 8 + f] = o;
        }
    }
}

// ---------------- layer 2 GEMM: h2 = hout @ W2, fused es2/ed2 ----------------
// block = 64 threads, 4 rows per block (16 out features each)
__global__ void __launch_bounds__(64) gemm2(const float* __restrict__ hin, const float* __restrict__ W2,
                      const float* __restrict__ a_src, const float* __restrict__ a_dst,
                      float* __restrict__ h2, float* __restrict__ es, float* __restrict__ ed) {
    __shared__ float hs[4][HID];
    __shared__ float os[4][OUTF];
    int tid = threadIdx.x;          // 0..63
    int i0 = blockIdx.x * 4;
    for (int t = tid; t < 4 * HID; t += 64)
        hs[t >> 6][t & 63] = hin[(size_t)i0 * HID + t];
    __syncthreads();
    int r = tid >> 4, f = tid & 15;
    float acc = 0.f;
#pragma unroll
    for (int k = 0; k < HID; ++k) acc += hs[r][k] * W2[k * OUTF + f];
    os[r][f] = acc;
    h2[(size_t)(i0 + r) * OUTF + f] = acc;
    __syncthreads();
    if (tid < 4) {
        float s1 = 0.f, s2 = 0.f;
#pragma unroll
        for (int ff = 0; ff < OUTF; ++ff) {
            s1 += os[tid][ff] * a_src[ff];
            s2 += os[tid][ff] * a_dst[ff];
        }
        es[i0 + tid] = s1;
        ed[i0 + tid] = s2;
    }
}

// ---------------- layer 2 attention + mean(1 head) + log_softmax ----------------
__global__ void __launch_bounds__(64) attn2(const uint32_t* __restrict__ mask,
    const float* __restrict__ h2, const float* __restrict__ es, const float* __restrict__ ed,
    float* __restrict__ out) {
    __shared__ int nbr[MAXNBR];
    __shared__ int cnt;
    int i = blockIdx.x;
    int lane = threadIdx.x;
    if (lane == 0) cnt = 0;
    __syncthreads();
    for (int w = lane; w < MASKW; w += 64) {
        uint32_t bits = mask[(size_t)i * MASKW + w];
        while (bits) {
            int b = __ffs(bits) - 1;
            bits &= bits - 1;
            int pos = atomicAdd(&cnt, 1);
            if (pos < MAXNBR) nbr[pos] = w * 32 + b;
        }
    }
    __syncthreads();
    int n = cnt < MAXNBR ? cnt : MAXNBR;
    float es_i = es[i];
    float m = -1e30f, s = 0.f;
    float acc[OUTF];
#pragma unroll
    for (int f = 0; f < OUTF; ++f) acc[f] = 0.f;
    for (int t = lane; t < n; t += 64) {
        int j = nbr[t];
        float v = es_i + ed[j];
        v = v > 0.f ? v : 0.2f * v;
        float nm = fmaxf(m, v);
        float sc = __expf(m - nm);
        float p  = __expf(v - nm);
        s = s * sc + p;
        const float* hj = h2 + (size_t)j * OUTF;
#pragma unroll
        for (int f = 0; f < OUTF; ++f) acc[f] = acc[f] * sc + p * hj[f];
        m = nm;
    }
#pragma unroll
    for (int off = 32; off >= 1; off >>= 1) {
        float mo = __shfl_xor(m, off, 64);
        float so = __shfl_xor(s, off, 64);
        float ao[OUTF];
#pragma unroll
        for (int f = 0; f < OUTF; ++f) ao[f] = __shfl_xor(acc[f], off, 64);
        float nm = fmaxf(m, mo);
        float c1 = __expf(m - nm), c2 = __expf(mo - nm);
        s = s * c1 + so * c2;
#pragma unroll
        for (int f = 0; f < OUTF; ++f) acc[f] = acc[f] * c1 + ao[f] * c2;
        m = nm;
    }
    if (lane == 0) {
        float inv = (s > 0.f) ? 1.f / s : 0.f;
        float v[OUTF];
        float mx = -1e30f;
#pragma unroll
        for (int f = 0; f < OUTF; ++f) {
            v[f] = acc[f] * inv;
            mx = fmaxf(mx, v[f]);
        }
        float se = 0.f;
#pragma unroll
        for (int f = 0; f < OUTF; ++f) se += __expf(v[f] - mx);
        float lse = mx + __logf(se);
#pragma unroll
        for (int f = 0; f < OUTF; ++f)
            out[(size_t)i * OUTF + f] = v[f] - lse;
    }
}

extern "C" void kernel_launch(void* const* d_in, const int* in_sizes, int n_in,
                              void* d_out, int out_size, void* d_ws, size_t ws_size,
                              hipStream_t stream) {
    const float* x   = (const float*)d_in[0];
    const int*   ei  = (const int*)d_in[1];
    const float* W1  = (const float*)d_in[2];
    const float* a1s = (const float*)d_in[3];
    const float* a1d = (const float*)d_in[4];
    const float* W2  = (const float*)d_in[5];
    const float* a2s = (const float*)d_in[6];
    const float* a2d = (const float*)d_in[7];
    float* out = (float*)d_out;
    int E = in_sizes[1] / 2;

    char* ws = (char*)d_ws;
    uint32_t* mask = (uint32_t*)ws;                // 2 MiB
    float* h1   = (float*)(ws + 2097152);          // 1 MiB   [N][64]
    float* es1  = (float*)(ws + 3145728);          // 128 KiB [8][N]
    float* ed1  = (float*)(ws + 3276800);          // 128 KiB [8][N]
    float* hout = (float*)(ws + 3407872);          // 1 MiB   [N][64]
    float* h2   = (float*)(ws + 4456448);          // 256 KiB [N][16]
    float* es2  = (float*)(ws + 4718592);          // 16 KiB  [N]
    float* ed2  = (float*)(ws + 4734976);          // 16 KiB  [N]

    hipMemsetAsync(mask, 0, NNODES * MASKW * sizeof(uint32_t), stream);
    scatter_edges<<<(E + 255) / 256, 256, 0, stream>>>(ei, E, mask);
    gemm1<<<NNODES / 8, 512, 0, stream>>>(x, W1, a1s, a1d, h1, es1, ed1);
    attn1<<<NNODES, 512, 0, stream>>>(mask, h1, es1, ed1, hout);
    gemm2<<<NNODES / 4, 64, 0, stream>>>(hout, W2, a2s, a2d, h2, es2, ed2);
    attn2<<<NNODES, 64, 0, stream>>>(mask, h2, es2, ed2, out);
}

// Round 7
// 133.009 us; speedup vs baseline: 1.2338x; 1.0085x over previous
//
#include <hip/hip_runtime.h>
#include <hip/hip_bf16.h>
#include <stdint.h>

#define NNODES 4096
#define MASKW  (NNODES / 32)   // 128 uint32 words per adjacency row
#define IN_F   512
#define HID    64
#define OUTF   16
#define CAP    512             // max neighbors kept per node (Poisson(~64); P(>128)~1e-12)

// ---------------- edge scatter: build symmetric adjacency bitmask ----------------
__global__ void scatter_edges(const int* __restrict__ ei, int E, uint32_t* __restrict__ mask) {
    int e = blockIdx.x * blockDim.x + threadIdx.x;
    if (e >= E) return;
    int u = ei[e], v = ei[E + e];
    if ((unsigned)u < NNODES && (unsigned)v < NNODES) {
        atomicOr(&mask[(size_t)u * MASKW + (v >> 5)], 1u << (v & 31));
        atomicOr(&mask[(size_t)v * MASKW + (u >> 5)], 1u << (u & 31));
    }
}

// ---------------- layer 1 GEMM: h1 = x @ W1, fused es/ed projections ----------------
// block = 512 threads = 8 waves; 8 rows per block; split-K: wave w owns k in [w*64, w*64+64)
__global__ void __launch_bounds__(512) gemm1(const float* __restrict__ x, const float* __restrict__ W1,
                      const float* __restrict__ a_src, const float* __restrict__ a_dst,
                      float* __restrict__ h1, float* __restrict__ es, float* __restrict__ ed) {
    __shared__ float xs[8][IN_F];        // 16 KB (reused as hs[8][64] after compute)
    __shared__ float part[8][8][HID];    // 16 KB  [wave][row][feat]
    int tid = threadIdx.x;
    int w = tid >> 6, f = tid & 63;
    int i0 = blockIdx.x * 8;

    const float4* xv = (const float4*)(x + (size_t)i0 * IN_F);
    float4* xsv = (float4*)&xs[0][0];
    xsv[tid] = xv[tid];
    xsv[tid + 512] = xv[tid + 512];
    __syncthreads();

    float acc[8];
#pragma unroll
    for (int r = 0; r < 8; ++r) acc[r] = 0.f;
    int k0 = w * 64;
    for (int k = k0; k < k0 + 64; k += 4) {
        float w0 = W1[(k + 0) * HID + f];
        float w1_ = W1[(k + 1) * HID + f];
        float w2 = W1[(k + 2) * HID + f];
        float w3 = W1[(k + 3) * HID + f];
#pragma unroll
        for (int r = 0; r < 8; ++r) {
            float4 xr = *(const float4*)&xs[r][k];   // broadcast ds_read_b128
            acc[r] += xr.x * w0 + xr.y * w1_ + xr.z * w2 + xr.w * w3;
        }
    }
#pragma unroll
    for (int r = 0; r < 8; ++r) part[w][r][f] = acc[r];
    __syncthreads();

    {
        int r = tid >> 6, ff = tid & 63;
        float v = 0.f;
#pragma unroll
        for (int p = 0; p < 8; ++p) v += part[p][r][ff];
        h1[(size_t)(i0 + r) * HID + ff] = v;
        xs[r][ff] = v;                   // reuse xs as hs
    }
    __syncthreads();

    if (tid < 64) {
        int r = tid >> 3, h = tid & 7;
        float s1 = 0.f, s2 = 0.f;
#pragma unroll
        for (int ff = 0; ff < 8; ++ff) {
            float hv = xs[r][h * 8 + ff];
            s1 += hv * a_src[h * 8 + ff];
            s2 += hv * a_dst[h * 8 + ff];
        }
        es[h * NNODES + (i0 + r)] = s1;
        ed[h * NNODES + (i0 + r)] = s2;
    }
}

// ---------------- layer 1 attention + fused layer-2 GEMM ----------------
// 1 block per node, 512 threads = 8 waves = 8 heads.
// Wave 0 builds the neighbor list by ballot/prefix compaction (no atomics).
// Epilogue computes h2 = elu(hout) @ W2 and es2/ed2 (layer-2 gemm fused).
__global__ void __launch_bounds__(512) attn1_fused(const uint32_t* __restrict__ mask,
    const float* __restrict__ h1, const float* __restrict__ es, const float* __restrict__ ed,
    const float* __restrict__ W2, const float* __restrict__ a2s, const float* __restrict__ a2d,
    float* __restrict__ h2, float* __restrict__ es2, float* __restrict__ ed2) {
    __shared__ int nbr[CAP];
    __shared__ float hs[HID];            // elu'd hout row
    __shared__ float part[4][OUTF];
    __shared__ int degs;
    int i = blockIdx.x;
    int tid = threadIdx.x;
    int h = tid >> 6, lane = tid & 63;

    // wave 0: atomic-free neighbor compaction (2 mask words per lane)
    if (tid < 64) {
        uint32_t b0 = mask[(size_t)i * MASKW + 2 * tid];
        uint32_t b1 = mask[(size_t)i * MASKW + 2 * tid + 1];
        int cnt = __popc(b0) + __popc(b1);
        int incl = cnt;
#pragma unroll
        for (int d = 1; d < 64; d <<= 1) {
            int t = __shfl_up(incl, d, 64);
            if (tid >= d) incl += t;
        }
        int pos = incl - cnt;
        int base = tid * 64;
        while (b0) { int b = __ffs(b0) - 1; b0 &= b0 - 1; if (pos < CAP) nbr[pos] = base + b; ++pos; }
        base += 32;
        while (b1) { int b = __ffs(b1) - 1; b1 &= b1 - 1; if (pos < CAP) nbr[pos] = base + b; ++pos; }
        if (tid == 63) degs = (incl < CAP) ? incl : CAP;
    }
    __syncthreads();
    int n = degs;

    float es_i = es[h * NNODES + i];
    const float* edh = ed + h * NNODES;
    float m = -1e30f, s = 0.f;
    float acc[8];
#pragma unroll
    for (int f = 0; f < 8; ++f) acc[f] = 0.f;
    for (int t = lane; t < n; t += 64) {
        int j = nbr[t];
        float v = es_i + edh[j];
        v = v > 0.f ? v : 0.2f * v;          // leaky_relu slope 0.2
        float nm = fmaxf(m, v);
        float sc = __expf(m - nm);
        float p  = __expf(v - nm);
        s = s * sc + p;
        const float4* hj = (const float4*)(h1 + (size_t)j * HID + h * 8);
        float4 h0 = hj[0], h1v = hj[1];
        acc[0] = acc[0] * sc + p * h0.x; acc[1] = acc[1] * sc + p * h0.y;
        acc[2] = acc[2] * sc + p * h0.z; acc[3] = acc[3] * sc + p * h0.w;
        acc[4] = acc[4] * sc + p * h1v.x; acc[5] = acc[5] * sc + p * h1v.y;
        acc[6] = acc[6] * sc + p * h1v.z; acc[7] = acc[7] * sc + p * h1v.w;
        m = nm;
    }
#pragma unroll
    for (int off = 32; off >= 1; off >>= 1) {
        float mo = __shfl_xor(m, off, 64);
        float so = __shfl_xor(s, off, 64);
        float ao[8];
#pragma unroll
        for (int f = 0; f < 8; ++f) ao[f] = __shfl_xor(acc[f], off, 64);
        float nm = fmaxf(m, mo);
        float c1 = __expf(m - nm), c2 = __expf(mo - nm);
        s = s * c1 + so * c2;
#pragma unroll
        for (int f = 0; f < 8; ++f) acc[f] = acc[f] * c1 + ao[f] * c2;
        m = nm;
    }
    if (lane == 0) {
        float inv = (s > 0.f) ? 1.f / s : 0.f;
#pragma unroll
        for (int f = 0; f < 8; ++f) {
            float o = acc[f] * inv;
            o = o > 0.f ? o : (__expf(o) - 1.f);   // ELU fused
            hs[h * 8 + f] = o;
        }
    }
    __syncthreads();

    // fused layer-2 GEMM: h2[i] = hs @ W2  (64x16), split over 4 k-quarters
    if (tid < 64) {
        int q = tid >> 4, f = tid & 15;
        float p = 0.f;
#pragma unroll
        for (int k = 16 * q; k < 16 * q + 16; ++k) p += hs[k] * W2[k * OUTF + f];
        part[q][f] = p;
    }
    __syncthreads();
    if (tid < OUTF) {
        float v = part[0][tid] + part[1][tid] + part[2][tid] + part[3][tid];
        h2[(size_t)i * OUTF + tid] = v;
        hs[tid] = v;
    }
    __syncthreads();
    if (tid == 0) {
        float s1 = 0.f, s2 = 0.f;
#pragma unroll
        for (int f = 0; f < OUTF; ++f) { s1 += hs[f] * a2s[f]; s2 += hs[f] * a2d[f]; }
        es2[i] = s1;
        ed2[i] = s2;
    }
}

// ---------------- layer 2 attention + mean(1 head) + log_softmax ----------------
// block = 256 threads = 4 waves; wave w handles node blockIdx*4+w with its own LDS list
__global__ void __launch_bounds__(256) attn2(const uint32_t* __restrict__ mask,
    const float* __restrict__ h2, const float* __restrict__ es, const float* __restrict__ ed,
    float* __restrict__ out) {
    __shared__ int nbr[4][CAP];
    int tid = threadIdx.x;
    int wid = tid >> 6, lane = tid & 63;
    int i = blockIdx.x * 4 + wid;

    uint32_t b0 = mask[(size_t)i * MASKW + 2 * lane];
    uint32_t b1 = mask[(size_t)i * MASKW + 2 * lane + 1];
    int cnt = __popc(b0) + __popc(b1);
    int incl = cnt;
#pragma unroll
    for (int d = 1; d < 64; d <<= 1) {
        int t = __shfl_up(incl, d, 64);
        if (lane >= d) incl += t;
    }
    int pos = incl - cnt;
    int base = lane * 64;
    int* myn = &nbr[wid][0];
    while (b0) { int b = __ffs(b0) - 1; b0 &= b0 - 1; if (pos < CAP) myn[pos] = base + b; ++pos; }
    base += 32;
    while (b1) { int b = __ffs(b1) - 1; b1 &= b1 - 1; if (pos < CAP) myn[pos] = base + b; ++pos; }
    int n = __shfl(incl, 63, 64);
    n = n < CAP ? n : CAP;
    __syncthreads();   // cross-lane LDS visibility (all 4 waves pass once)

    float es_i = es[i];
    float m = -1e30f, s = 0.f;
    float acc[OUTF];
#pragma unroll
    for (int f = 0; f < OUTF; ++f) acc[f] = 0.f;
    for (int t = lane; t < n; t += 64) {
        int j = myn[t];
        float v = es_i + ed[j];
        v = v > 0.f ? v : 0.2f * v;
        float nm = fmaxf(m, v);
        float sc = __expf(m - nm);
        float p  = __expf(v - nm);
        s = s * sc + p;
        const float4* hj = (const float4*)(h2 + (size_t)j * OUTF);
        float4 q0 = hj[0], q1 = hj[1], q2 = hj[2], q3 = hj[3];
        acc[0]  = acc[0]  * sc + p * q0.x; acc[1]  = acc[1]  * sc + p * q0.y;
        acc[2]  = acc[2]  * sc + p * q0.z; acc[3]  = acc[3]  * sc + p * q0.w;
        acc[4]  = acc[4]  * sc + p * q1.x; acc[5]  = acc[5]  * sc + p * q1.y;
        acc[6]  = acc[6]  * sc + p * q1.z; acc[7]  = acc[7]  * sc + p * q1.w;
        acc[8]  = acc[8]  * sc + p * q2.x; acc[9]  = acc[9]  * sc + p * q2.y;
        acc[10] = acc[10] * sc + p * q2.z; acc[11] = acc[11] * sc + p * q2.w;
        acc[12] = acc[12] * sc + p * q3.x; acc[13] = acc[13] * sc + p * q3.y;
        acc[14] = acc[14] * sc + p * q3.z; acc[15] = acc[15] * sc + p * q3.w;
        m = nm;
    }
#pragma unroll
    for (int off = 32; off >= 1; off >>= 1) {
        float mo = __shfl_xor(m, off, 64);
        float so = __shfl_xor(s, off, 64);
        float ao[OUTF];
#pragma unroll
        for (int f = 0; f < OUTF; ++f) ao[f] = __shfl_xor(acc[f], off, 64);
        float nm = fmaxf(m, mo);
        float c1 = __expf(m - nm), c2 = __expf(mo - nm);
        s = s * c1 + so * c2;
#pragma unroll
        for (int f = 0; f < OUTF; ++f) acc[f] = acc[f] * c1 + ao[f] * c2;
        m = nm;
    }
    if (lane == 0) {
        float inv = (s > 0.f) ? 1.f / s : 0.f;
        float v[OUTF];
        float mx = -1e30f;
#pragma unroll
        for (int f = 0; f < OUTF; ++f) {
            v[f] = acc[f] * inv;
            mx = fmaxf(mx, v[f]);
        }
        float se = 0.f;
#pragma unroll
        for (int f = 0; f < OUTF; ++f) se += __expf(v[f] - mx);
        float lse = mx + __logf(se);
#pragma unroll
        for (int f = 0; f < OUTF; ++f)
            out[(size_t)i * OUTF + f] = v[f] - lse;
    }
}

extern "C" void kernel_launch(void* const* d_in, const int* in_sizes, int n_in,
                              void* d_out, int out_size, void* d_ws, size_t ws_size,
                              hipStream_t stream) {
    const float* x   = (const float*)d_in[0];
    const int*   ei  = (const int*)d_in[1];
    const float* W1  = (const float*)d_in[2];
    const float* a1s = (const float*)d_in[3];
    const float* a1d = (const float*)d_in[4];
    const float* W2  = (const float*)d_in[5];
    const float* a2s = (const float*)d_in[6];
    const float* a2d = (const float*)d_in[7];
    float* out = (float*)d_out;
    int E = in_sizes[1] / 2;

    char* ws = (char*)d_ws;
    uint32_t* mask = (uint32_t*)ws;                // 2 MiB
    float* h1   = (float*)(ws + 2097152);          // 1 MiB   [N][64]
    float* es1  = (float*)(ws + 3145728);          // 128 KiB [8][N]
    float* ed1  = (float*)(ws + 3276800);          // 128 KiB [8][N]
    float* h2   = (float*)(ws + 3407872);          // 256 KiB [N][16]
    float* es2  = (float*)(ws + 3670016);          // 16 KiB  [N]
    float* ed2  = (float*)(ws + 3686400);          // 16 KiB  [N]

    hipMemsetAsync(mask, 0, NNODES * MASKW * sizeof(uint32_t), stream);
    scatter_edges<<<(E + 255) / 256, 256, 0, stream>>>(ei, E, mask);
    gemm1<<<NNODES / 8, 512, 0, stream>>>(x, W1, a1s, a1d, h1, es1, ed1);
    attn1_fused<<<NNODES, 512, 0, stream>>>(mask, h1, es1, ed1, W2, a2s, a2d, h2, es2, ed2);
    attn2<<<NNODES / 4, 256, 0, stream>>>(mask, h2, es2, ed2, out);
}

// Round 8
// 131.548 us; speedup vs baseline: 1.2475x; 1.0111x over previous
//
#include <hip/hip_runtime.h>
#include <hip/hip_bf16.h>
#include <stdint.h>

#define NNODES 4096
#define MASKW  (NNODES / 32)   // 128 uint32 words per adjacency row
#define IN_F   512
#define HID    64
#define OUTF   16
#define CAP    512             // max neighbors kept per node (Poisson(~64); P(>512)~0)

// ---------------- edge scatter: build symmetric adjacency bitmask ----------------
// (mask is zeroed by gemm1, which runs before this on the same stream)
__global__ void scatter_edges(const int* __restrict__ ei, int E, uint32_t* __restrict__ mask) {
    int e = blockIdx.x * blockDim.x + threadIdx.x;
    if (e >= E) return;
    int u = ei[e], v = ei[E + e];
    if ((unsigned)u < NNODES && (unsigned)v < NNODES) {
        atomicOr(&mask[(size_t)u * MASKW + (v >> 5)], 1u << (v & 31));
        atomicOr(&mask[(size_t)v * MASKW + (u >> 5)], 1u << (u & 31));
    }
}

// ---------------- layer 1 GEMM: h1 = x @ W1, fused es/ed projections ----------------
// block = 512 threads = 8 waves; 8 rows per block; split-K: wave w owns k in [w*64, w*64+64)
// Also zeroes the adjacency mask (saves the separate memset dispatch).
__global__ void __launch_bounds__(512) gemm1(const float* __restrict__ x, const float* __restrict__ W1,
                      const float* __restrict__ a_src, const float* __restrict__ a_dst,
                      float* __restrict__ h1, float* __restrict__ es, float* __restrict__ ed,
                      uint32_t* __restrict__ mask) {
    __shared__ float xs[8][IN_F];        // 16 KB (reused as hs[8][64] after compute)
    __shared__ float part[8][8][HID];    // 16 KB  [wave][row][feat]
    int tid = threadIdx.x;
    int w = tid >> 6, f = tid & 63;
    int i0 = blockIdx.x * 8;

    // zero the 2 MiB mask: 512 blocks x 512 threads x 1 uint2 = 2 MiB
    ((uint2*)mask)[blockIdx.x * 512 + tid] = make_uint2(0u, 0u);

    const float4* xv = (const float4*)(x + (size_t)i0 * IN_F);
    float4* xsv = (float4*)&xs[0][0];
    xsv[tid] = xv[tid];
    xsv[tid + 512] = xv[tid + 512];
    __syncthreads();

    float acc[8];
#pragma unroll
    for (int r = 0; r < 8; ++r) acc[r] = 0.f;
    int k0 = w * 64;
    for (int k = k0; k < k0 + 64; k += 4) {
        float w0 = W1[(k + 0) * HID + f];
        float w1_ = W1[(k + 1) * HID + f];
        float w2 = W1[(k + 2) * HID + f];
        float w3 = W1[(k + 3) * HID + f];
#pragma unroll
        for (int r = 0; r < 8; ++r) {
            float4 xr = *(const float4*)&xs[r][k];   // broadcast ds_read_b128
            acc[r] += xr.x * w0 + xr.y * w1_ + xr.z * w2 + xr.w * w3;
        }
    }
#pragma unroll
    for (int r = 0; r < 8; ++r) part[w][r][f] = acc[r];
    __syncthreads();

    {
        int r = tid >> 6, ff = tid & 63;
        float v = 0.f;
#pragma unroll
        for (int p = 0; p < 8; ++p) v += part[p][r][ff];
        h1[(size_t)(i0 + r) * HID + ff] = v;
        xs[r][ff] = v;                   // reuse xs as hs
    }
    __syncthreads();

    if (tid < 64) {
        int r = tid >> 3, h = tid & 7;
        float s1 = 0.f, s2 = 0.f;
#pragma unroll
        for (int ff = 0; ff < 8; ++ff) {
            float hv = xs[r][h * 8 + ff];
            s1 += hv * a_src[h * 8 + ff];
            s2 += hv * a_dst[h * 8 + ff];
        }
        es[h * NNODES + (i0 + r)] = s1;
        ed[h * NNODES + (i0 + r)] = s2;
    }
}

// ---------------- layer 1 attention + fused layer-2 GEMM ----------------
// 1 block per node, 512 threads = 8 waves = 8 heads.
// Wave 0 builds the neighbor list by ballot/prefix compaction (no atomics).
// Softmax without max-shift: scores are bounded (|v| <~ 2), exp(v) safe in fp32,
// and softmax is shift-invariant -> identical result, no online rescale needed.
// Epilogue computes h2 = elu(hout) @ W2 and es2/ed2 (layer-2 gemm fused).
__global__ void __launch_bounds__(512) attn1_fused(const uint32_t* __restrict__ mask,
    const float* __restrict__ h1, const float* __restrict__ es, const float* __restrict__ ed,
    const float* __restrict__ W2, const float* __restrict__ a2s, const float* __restrict__ a2d,
    float* __restrict__ h2, float* __restrict__ es2, float* __restrict__ ed2) {
    __shared__ int nbr[CAP];
    __shared__ float hs[HID];            // elu'd hout row
    __shared__ float part[4][OUTF];
    __shared__ int degs;
    int i = blockIdx.x;
    int tid = threadIdx.x;
    int h = tid >> 6, lane = tid & 63;

    // wave 0: atomic-free neighbor compaction (2 mask words per lane)
    if (tid < 64) {
        uint32_t b0 = mask[(size_t)i * MASKW + 2 * tid];
        uint32_t b1 = mask[(size_t)i * MASKW + 2 * tid + 1];
        int cnt = __popc(b0) + __popc(b1);
        int incl = cnt;
#pragma unroll
        for (int d = 1; d < 64; d <<= 1) {
            int t = __shfl_up(incl, d, 64);
            if (tid >= d) incl += t;
        }
        int pos = incl - cnt;
        int base = tid * 64;
        while (b0) { int b = __ffs(b0) - 1; b0 &= b0 - 1; if (pos < CAP) nbr[pos] = base + b; ++pos; }
        base += 32;
        while (b1) { int b = __ffs(b1) - 1; b1 &= b1 - 1; if (pos < CAP) nbr[pos] = base + b; ++pos; }
        if (tid == 63) degs = (incl < CAP) ? incl : CAP;
    }
    __syncthreads();
    int n = degs;

    float es_i = es[h * NNODES + i];
    const float* edh = ed + h * NNODES;
    float s = 0.f;
    float acc[8];
#pragma unroll
    for (int f = 0; f < 8; ++f) acc[f] = 0.f;
    for (int t = lane; t < n; t += 64) {
        int j = nbr[t];
        float v = es_i + edh[j];
        v = v > 0.f ? v : 0.2f * v;          // leaky_relu slope 0.2
        float p = __expf(v);
        s += p;
        const float4* hj = (const float4*)(h1 + (size_t)j * HID + h * 8);
        float4 h0 = hj[0], h1v = hj[1];
        acc[0] += p * h0.x;  acc[1] += p * h0.y;
        acc[2] += p * h0.z;  acc[3] += p * h0.w;
        acc[4] += p * h1v.x; acc[5] += p * h1v.y;
        acc[6] += p * h1v.z; acc[7] += p * h1v.w;
    }
    // butterfly sum of (s, acc[8]) across the 64-lane wave
#pragma unroll
    for (int off = 32; off >= 1; off >>= 1) {
        s += __shfl_xor(s, off, 64);
#pragma unroll
        for (int f = 0; f < 8; ++f) acc[f] += __shfl_xor(acc[f], off, 64);
    }
    if (lane == 0) {
        float inv = (s > 0.f) ? 1.f / s : 0.f;
#pragma unroll
        for (int f = 0; f < 8; ++f) {
            float o = acc[f] * inv;
            o = o > 0.f ? o : (__expf(o) - 1.f);   // ELU fused
            hs[h * 8 + f] = o;
        }
    }
    __syncthreads();

    // fused layer-2 GEMM: h2[i] = hs @ W2  (64x16), split over 4 k-quarters
    if (tid < 64) {
        int q = tid >> 4, f = tid & 15;
        float p = 0.f;
#pragma unroll
        for (int k = 16 * q; k < 16 * q + 16; ++k) p += hs[k] * W2[k * OUTF + f];
        part[q][f] = p;
    }
    __syncthreads();
    if (tid < OUTF) {
        float v = part[0][tid] + part[1][tid] + part[2][tid] + part[3][tid];
        h2[(size_t)i * OUTF + tid] = v;
        hs[tid] = v;
    }
    __syncthreads();
    if (tid == 0) {
        float s1 = 0.f, s2 = 0.f;
#pragma unroll
        for (int f = 0; f < OUTF; ++f) { s1 += hs[f] * a2s[f]; s2 += hs[f] * a2d[f]; }
        es2[i] = s1;
        ed2[i] = s2;
    }
}

// ---------------- layer 2 attention + mean(1 head) + log_softmax ----------------
// block = 256 threads = 4 waves; wave w handles node blockIdx*4+w with its own LDS list
__global__ void __launch_bounds__(256) attn2(const uint32_t* __restrict__ mask,
    const float* __restrict__ h2, const float* __restrict__ es, const float* __restrict__ ed,
    float* __restrict__ out) {
    __shared__ int nbr[4][CAP];
    int tid = threadIdx.x;
    int wid = tid >> 6, lane = tid & 63;
    int i = blockIdx.x * 4 + wid;

    uint32_t b0 = mask[(size_t)i * MASKW + 2 * lane];
    uint32_t b1 = mask[(size_t)i * MASKW + 2 * lane + 1];
    int cnt = __popc(b0) + __popc(b1);
    int incl = cnt;
#pragma unroll
    for (int d = 1; d < 64; d <<= 1) {
        int t = __shfl_up(incl, d, 64);
        if (lane >= d) incl += t;
    }
    int pos = incl - cnt;
    int base = lane * 64;
    int* myn = &nbr[wid][0];
    while (b0) { int b = __ffs(b0) - 1; b0 &= b0 - 1; if (pos < CAP) myn[pos] = base + b; ++pos; }
    base += 32;
    while (b1) { int b = __ffs(b1) - 1; b1 &= b1 - 1; if (pos < CAP) myn[pos] = base + b; ++pos; }
    int n = __shfl(incl, 63, 64);
    n = n < CAP ? n : CAP;
    __syncthreads();   // cross-lane LDS visibility (all 4 waves pass once)

    float es_i = es[i];
    float s = 0.f;
    float acc[OUTF];
#pragma unroll
    for (int f = 0; f < OUTF; ++f) acc[f] = 0.f;
    for (int t = lane; t < n; t += 64) {
        int j = myn[t];
        float v = es_i + ed[j];
        v = v > 0.f ? v : 0.2f * v;
        float p = __expf(v);
        s += p;
        const float4* hj = (const float4*)(h2 + (size_t)j * OUTF);
        float4 q0 = hj[0], q1 = hj[1], q2 = hj[2], q3 = hj[3];
        acc[0]  += p * q0.x; acc[1]  += p * q0.y;
        acc[2]  += p * q0.z; acc[3]  += p * q0.w;
        acc[4]  += p * q1.x; acc[5]  += p * q1.y;
        acc[6]  += p * q1.z; acc[7]  += p * q1.w;
        acc[8]  += p * q2.x; acc[9]  += p * q2.y;
        acc[10] += p * q2.z; acc[11] += p * q2.w;
        acc[12] += p * q3.x; acc[13] += p * q3.y;
        acc[14] += p * q3.z; acc[15] += p * q3.w;
    }
#pragma unroll
    for (int off = 32; off >= 1; off >>= 1) {
        s += __shfl_xor(s, off, 64);
#pragma unroll
        for (int f = 0; f < OUTF; ++f) acc[f] += __shfl_xor(acc[f], off, 64);
    }
    if (lane == 0) {
        float inv = (s > 0.f) ? 1.f / s : 0.f;
        float v[OUTF];
        float mx = -1e30f;
#pragma unroll
        for (int f = 0; f < OUTF; ++f) {
            v[f] = acc[f] * inv;
            mx = fmaxf(mx, v[f]);
        }
        float se = 0.f;
#pragma unroll
        for (int f = 0; f < OUTF; ++f) se += __expf(v[f] - mx);
        float lse = mx + __logf(se);
#pragma unroll
        for (int f = 0; f < OUTF; ++f)
            out[(size_t)i * OUTF + f] = v[f] - lse;
    }
}

extern "C" void kernel_launch(void* const* d_in, const int* in_sizes, int n_in,
                              void* d_out, int out_size, void* d_ws, size_t ws_size,
                              hipStream_t stream) {
    const float* x   = (const float*)d_in[0];
    const int*   ei  = (const int*)d_in[1];
    const float* W1  = (const float*)d_in[2];
    const float* a1s = (const float*)d_in[3];
    const float* a1d = (const float*)d_in[4];
    const float* W2  = (const float*)d_in[5];
    const float* a2s = (const float*)d_in[6];
    const float* a2d = (const float*)d_in[7];
    float* out = (float*)d_out;
    int E = in_sizes[1] / 2;

    char* ws = (char*)d_ws;
    uint32_t* mask = (uint32_t*)ws;                // 2 MiB
    float* h1   = (float*)(ws + 2097152);          // 1 MiB   [N][64]
    float* es1  = (float*)(ws + 3145728);          // 128 KiB [8][N]
    float* ed1  = (float*)(ws + 3276800);          // 128 KiB [8][N]
    float* h2   = (float*)(ws + 3407872);          // 256 KiB [N][16]
    float* es2  = (float*)(ws + 3670016);          // 16 KiB  [N]
    float* ed2  = (float*)(ws + 3686400);          // 16 KiB  [N]

    // gemm1 zeroes mask (it precedes scatter_edges in stream order)
    gemm1<<<NNODES / 8, 512, 0, stream>>>(x, W1, a1s, a1d, h1, es1, ed1, mask);
    scatter_edges<<<(E + 255) / 256, 256, 0, stream>>>(ei, E, mask);
    attn1_fused<<<NNODES, 512, 0, stream>>>(mask, h1, es1, ed1, W2, a2s, a2d, h2, es2, ed2);
    attn2<<<NNODES / 4, 256, 0, stream>>>(mask, h2, es2, ed2, out);
}

// Round 9
// 129.387 us; speedup vs baseline: 1.2683x; 1.0167x over previous
//
#include <hip/hip_runtime.h>
#include <hip/hip_bf16.h>
#include <stdint.h>

#define NNODES 4096
#define MASKW  (NNODES / 32)   // 128 uint32 words per adjacency row
#define IN_F   512
#define HID    64
#define OUTF   16
#define CAP    512             // max neighbors kept per node (Poisson(~64); P(>512)~0)

// ---------------- edge scatter: build symmetric adjacency bitmask ----------------
// (mask is zeroed by gemm1, which runs before this on the same stream)
__global__ void scatter_edges(const int* __restrict__ ei, int E, uint32_t* __restrict__ mask) {
    int e = blockIdx.x * blockDim.x + threadIdx.x;
    if (e >= E) return;
    int u = ei[e], v = ei[E + e];
    if ((unsigned)u < NNODES && (unsigned)v < NNODES) {
        atomicOr(&mask[(size_t)u * MASKW + (v >> 5)], 1u << (v & 31));
        atomicOr(&mask[(size_t)v * MASKW + (u >> 5)], 1u << (u & 31));
    }
}

// ---------------- layer 1 GEMM: h1 = x @ W1, fused es/ed projections ----------------
// block = 512 threads = 8 waves; 8 rows per block; split-K: wave w owns k in [w*64, w*64+64).
// x is read via SCALAR loads (wave-uniform addresses, forced by readfirstlane) -> s_load_dwordx4,
// no LDS staging in the hot loop. W1 via per-lane vector loads. Also zeroes the adjacency mask.
__global__ void __launch_bounds__(512) gemm1(const float* __restrict__ x, const float* __restrict__ W1,
                      const float* __restrict__ a_src, const float* __restrict__ a_dst,
                      float* __restrict__ h1, float* __restrict__ es, float* __restrict__ ed,
                      uint32_t* __restrict__ mask) {
    __shared__ float part[8][8][HID];    // 16 KB  [wave][row][feat]
    __shared__ float hs[8][HID];         // 2 KB   final h rows for es/ed epilogue
    int tid = threadIdx.x;
    int w = __builtin_amdgcn_readfirstlane(tid >> 6);   // wave id, provably uniform
    int f = tid & 63;
    int i0 = blockIdx.x * 8;

    // zero the 2 MiB mask: 512 blocks x 512 threads x 1 uint2 = 2 MiB
    ((uint2*)mask)[blockIdx.x * 512 + tid] = make_uint2(0u, 0u);

    float acc[8];
#pragma unroll
    for (int r = 0; r < 8; ++r) acc[r] = 0.f;

    const float* Wp = W1 + (size_t)(w * 64) * HID + f;       // per-lane column base
    const float* xbase = x + (size_t)i0 * IN_F + w * 64;     // uniform base for this wave

    for (int k = 0; k < 64; k += 4) {
        float w0 = Wp[(k + 0) * HID];
        float w1_ = Wp[(k + 1) * HID];
        float w2 = Wp[(k + 2) * HID];
        float w3 = Wp[(k + 3) * HID];
#pragma unroll
        for (int r = 0; r < 8; ++r) {
            const float* xr = xbase + (size_t)r * IN_F + k;  // uniform -> s_load_dwordx4
            float x0 = xr[0], x1 = xr[1], x2 = xr[2], x3 = xr[3];
            acc[r] += x0 * w0 + x1 * w1_ + x2 * w2 + x3 * w3;
        }
    }
#pragma unroll
    for (int r = 0; r < 8; ++r) part[w][r][f] = acc[r];
    __syncthreads();

    // reduce the 8 K-slices: 512 outputs, one per thread
    {
        int r = tid >> 6, ff = tid & 63;
        float v = 0.f;
#pragma unroll
        for (int p = 0; p < 8; ++p) v += part[p][r][ff];
        h1[(size_t)(i0 + r) * HID + ff] = v;
        hs[r][ff] = v;
    }
    __syncthreads();

    // es/ed: thread t<64 handles (row r = t>>3, head h = t&7); F1 = 8
    if (tid < 64) {
        int r = tid >> 3, h = tid & 7;
        float s1 = 0.f, s2 = 0.f;
#pragma unroll
        for (int ff = 0; ff < 8; ++ff) {
            float hv = hs[r][h * 8 + ff];
            s1 += hv * a_src[h * 8 + ff];
            s2 += hv * a_dst[h * 8 + ff];
        }
        es[h * NNODES + (i0 + r)] = s1;
        ed[h * NNODES + (i0 + r)] = s2;
    }
}

// ---------------- layer 1 attention + fused layer-2 GEMM ----------------
// 1 block per node, 512 threads = 8 waves = 8 heads.
// Wave 0 builds the neighbor list by ballot/prefix compaction (no atomics).
// Softmax without max-shift: scores are bounded (|v| <~ 2), exp(v) safe in fp32,
// and softmax is shift-invariant -> identical result, no online rescale needed.
// Epilogue computes h2 = elu(hout) @ W2 and es2/ed2 (layer-2 gemm fused).
__global__ void __launch_bounds__(512) attn1_fused(const uint32_t* __restrict__ mask,
    const float* __restrict__ h1, const float* __restrict__ es, const float* __restrict__ ed,
    const float* __restrict__ W2, const float* __restrict__ a2s, const float* __restrict__ a2d,
    float* __restrict__ h2, float* __restrict__ es2, float* __restrict__ ed2) {
    __shared__ int nbr[CAP];
    __shared__ float hs[HID];            // elu'd hout row
    __shared__ float part[4][OUTF];
    __shared__ int degs;
    int i = blockIdx.x;
    int tid = threadIdx.x;
    int h = tid >> 6, lane = tid & 63;

    // wave 0: atomic-free neighbor compaction (2 mask words per lane)
    if (tid < 64) {
        uint32_t b0 = mask[(size_t)i * MASKW + 2 * tid];
        uint32_t b1 = mask[(size_t)i * MASKW + 2 * tid + 1];
        int cnt = __popc(b0) + __popc(b1);
        int incl = cnt;
#pragma unroll
        for (int d = 1; d < 64; d <<= 1) {
            int t = __shfl_up(incl, d, 64);
            if (tid >= d) incl += t;
        }
        int pos = incl - cnt;
        int base = tid * 64;
        while (b0) { int b = __ffs(b0) - 1; b0 &= b0 - 1; if (pos < CAP) nbr[pos] = base + b; ++pos; }
        base += 32;
        while (b1) { int b = __ffs(b1) - 1; b1 &= b1 - 1; if (pos < CAP) nbr[pos] = base + b; ++pos; }
        if (tid == 63) degs = (incl < CAP) ? incl : CAP;
    }
    __syncthreads();
    int n = degs;

    float es_i = es[h * NNODES + i];
    const float* edh = ed + h * NNODES;
    float s = 0.f;
    float acc[8];
#pragma unroll
    for (int f = 0; f < 8; ++f) acc[f] = 0.f;
    for (int t = lane; t < n; t += 64) {
        int j = nbr[t];
        float v = es_i + edh[j];
        v = v > 0.f ? v : 0.2f * v;          // leaky_relu slope 0.2
        float p = __expf(v);
        s += p;
        const float4* hj = (const float4*)(h1 + (size_t)j * HID + h * 8);
        float4 h0 = hj[0], h1v = hj[1];
        acc[0] += p * h0.x;  acc[1] += p * h0.y;
        acc[2] += p * h0.z;  acc[3] += p * h0.w;
        acc[4] += p * h1v.x; acc[5] += p * h1v.y;
        acc[6] += p * h1v.z; acc[7] += p * h1v.w;
    }
    // butterfly sum of (s, acc[8]) across the 64-lane wave
#pragma unroll
    for (int off = 32; off >= 1; off >>= 1) {
        s += __shfl_xor(s, off, 64);
#pragma unroll
        for (int f = 0; f < 8; ++f) acc[f] += __shfl_xor(acc[f], off, 64);
    }
    if (lane == 0) {
        float inv = (s > 0.f) ? 1.f / s : 0.f;
#pragma unroll
        for (int f = 0; f < 8; ++f) {
            float o = acc[f] * inv;
            o = o > 0.f ? o : (__expf(o) - 1.f);   // ELU fused
            hs[h * 8 + f] = o;
        }
    }
    __syncthreads();

    // fused layer-2 GEMM: h2[i] = hs @ W2  (64x16), split over 4 k-quarters
    if (tid < 64) {
        int q = tid >> 4, f = tid & 15;
        float p = 0.f;
#pragma unroll
        for (int k = 16 * q; k < 16 * q + 16; ++k) p += hs[k] * W2[k * OUTF + f];
        part[q][f] = p;
    }
    __syncthreads();
    if (tid < OUTF) {
        float v = part[0][tid] + part[1][tid] + part[2][tid] + part[3][tid];
        h2[(size_t)i * OUTF + tid] = v;
        hs[tid] = v;
    }
    __syncthreads();
    if (tid == 0) {
        float s1 = 0.f, s2 = 0.f;
#pragma unroll
        for (int f = 0; f < OUTF; ++f) { s1 += hs[f] * a2s[f]; s2 += hs[f] * a2d[f]; }
        es2[i] = s1;
        ed2[i] = s2;
    }
}

// ---------------- layer 2 attention + mean(1 head) + log_softmax ----------------
// block = 256 threads = 4 waves; wave w handles node blockIdx*4+w with its own LDS list
__global__ void __launch_bounds__(256) attn2(const uint32_t* __restrict__ mask,
    const float* __restrict__ h2, const float* __restrict__ es, const float* __restrict__ ed,
    float* __restrict__ out) {
    __shared__ int nbr[4][CAP];
    int tid = threadIdx.x;
    int wid = tid >> 6, lane = tid & 63;
    int i = blockIdx.x * 4 + wid;

    uint32_t b0 = mask[(size_t)i * MASKW + 2 * lane];
    uint32_t b1 = mask[(size_t)i * MASKW + 2 * lane + 1];
    int cnt = __popc(b0) + __popc(b1);
    int incl = cnt;
#pragma unroll
    for (int d = 1; d < 64; d <<= 1) {
        int t = __shfl_up(incl, d, 64);
        if (lane >= d) incl += t;
    }
    int pos = incl - cnt;
    int base = lane * 64;
    int* myn = &nbr[wid][0];
    while (b0) { int b = __ffs(b0) - 1; b0 &= b0 - 1; if (pos < CAP) myn[pos] = base + b; ++pos; }
    base += 32;
    while (b1) { int b = __ffs(b1) - 1; b1 &= b1 - 1; if (pos < CAP) myn[pos] = base + b; ++pos; }
    int n = __shfl(incl, 63, 64);
    n = n < CAP ? n : CAP;
    __syncthreads();   // cross-lane LDS visibility (all 4 waves pass once)

    float es_i = es[i];
    float s = 0.f;
    float acc[OUTF];
#pragma unroll
    for (int f = 0; f < OUTF; ++f) acc[f] = 0.f;
    for (int t = lane; t < n; t += 64) {
        int j = myn[t];
        float v = es_i + ed[j];
        v = v > 0.f ? v : 0.2f * v;
        float p = __expf(v);
        s += p;
        const float4* hj = (const float4*)(h2 + (size_t)j * OUTF);
        float4 q0 = hj[0], q1 = hj[1], q2 = hj[2], q3 = hj[3];
        acc[0]  += p * q0.x; acc[1]  += p * q0.y;
        acc[2]  += p * q0.z; acc[3]  += p * q0.w;
        acc[4]  += p * q1.x; acc[5]  += p * q1.y;
        acc[6]  += p * q1.z; acc[7]  += p * q1.w;
        acc[8]  += p * q2.x; acc[9]  += p * q2.y;
        acc[10] += p * q2.z; acc[11] += p * q2.w;
        acc[12] += p * q3.x; acc[13] += p * q3.y;
        acc[14] += p * q3.z; acc[15] += p * q3.w;
    }
#pragma unroll
    for (int off = 32; off >= 1; off >>= 1) {
        s += __shfl_xor(s, off, 64);
#pragma unroll
        for (int f = 0; f < OUTF; ++f) acc[f] += __shfl_xor(acc[f], off, 64);
    }
    if (lane == 0) {
        float inv = (s > 0.f) ? 1.f / s : 0.f;
        float v[OUTF];
        float mx = -1e30f;
#pragma unroll
        for (int f = 0; f < OUTF; ++f) {
            v[f] = acc[f] * inv;
            mx = fmaxf(mx, v[f]);
        }
        float se = 0.f;
#pragma unroll
        for (int f = 0; f < OUTF; ++f) se += __expf(v[f] - mx);
        float lse = mx + __logf(se);
#pragma unroll
        for (int f = 0; f < OUTF; ++f)
            out[(size_t)i * OUTF + f] = v[f] - lse;
    }
}

extern "C" void kernel_launch(void* const* d_in, const int* in_sizes, int n_in,
                              void* d_out, int out_size, void* d_ws, size_t ws_size,
                              hipStream_t stream) {
    const float* x   = (const float*)d_in[0];
    const int*   ei  = (const int*)d_in[1];
    const float* W1  = (const float*)d_in[2];
    const float* a1s = (const float*)d_in[3];
    const float* a1d = (const float*)d_in[4];
    const float* W2  = (const float*)d_in[5];
    const float* a2s = (const float*)d_in[6];
    const float* a2d = (const float*)d_in[7];
    float* out = (float*)d_out;
    int E = in_sizes[1] / 2;

    char* ws = (char*)d_ws;
    uint32_t* mask = (uint32_t*)ws;                // 2 MiB
    float* h1   = (float*)(ws + 2097152);          // 1 MiB   [N][64]
    float* es1  = (float*)(ws + 3145728);          // 128 KiB [8][N]
    float* ed1  = (float*)(ws + 3276800);          // 128 KiB [8][N]
    float* h2   = (float*)(ws + 3407872);          // 256 KiB [N][16]
    float* es2  = (float*)(ws + 3670016);          // 16 KiB  [N]
    float* ed2  = (float*)(ws + 3686400);          // 16 KiB  [N]

    // gemm1 zeroes mask (it precedes scatter_edges in stream order)
    gemm1<<<NNODES / 8, 512, 0, stream>>>(x, W1, a1s, a1d, h1, es1, ed1, mask);
    scatter_edges<<<(E + 255) / 256, 256, 0, stream>>>(ei, E, mask);
    attn1_fused<<<NNODES, 512, 0, stream>>>(mask, h1, es1, ed1, W2, a2s, a2d, h2, es2, ed2);
    attn2<<<NNODES / 4, 256, 0, stream>>>(mask, h2, es2, ed2, out);
}

// Round 11
// 128.834 us; speedup vs baseline: 1.2738x; 1.0043x over previous
//
#include <hip/hip_runtime.h>
#include <hip/hip_bf16.h>
#include <stdint.h>

#define NNODES 4096
#define MASKW  (NNODES / 32)   // 128 uint32 words per adjacency row
#define IN_F   512
#define HID    64
#define OUTF   16
#define CAP    512             // max neighbors kept per node (Poisson(~64); P(>512)~0)

// ---------------- edge scatter: build symmetric adjacency bitmask ----------------
// (mask is zeroed by gemm1, which runs before this on the same stream)
__global__ void scatter_edges(const int* __restrict__ ei, int E, uint32_t* __restrict__ mask) {
    int e = blockIdx.x * blockDim.x + threadIdx.x;
    if (e >= E) return;
    int u = ei[e], v = ei[E + e];
    if ((unsigned)u < NNODES && (unsigned)v < NNODES) {
        atomicOr(&mask[(size_t)u * MASKW + (v >> 5)], 1u << (v & 31));
        atomicOr(&mask[(size_t)v * MASKW + (u >> 5)], 1u << (u & 31));
    }
}

// ---------------- layer 1 GEMM: h1 = x @ W1, fused es/ed projections ----------------
// block = 512 threads = 8 waves; 8 rows per block; split-K: wave w owns k in [w*64, w*64+64).
// x is read via SCALAR loads (wave-uniform addresses, forced by readfirstlane) -> s_load_dwordx4,
// no LDS staging in the hot loop. W1 via per-lane vector loads. Also zeroes the adjacency mask.
__global__ void __launch_bounds__(512) gemm1(const float* __restrict__ x, const float* __restrict__ W1,
                      const float* __restrict__ a_src, const float* __restrict__ a_dst,
                      float* __restrict__ h1, float* __restrict__ es, float* __restrict__ ed,
                      uint32_t* __restrict__ mask) {
    __shared__ float part[8][8][HID];    // 16 KB  [wave][row][feat]
    __shared__ float hs[8][HID];         // 2 KB   final h rows for es/ed epilogue
    int tid = threadIdx.x;
    int w = __builtin_amdgcn_readfirstlane(tid >> 6);   // wave id, provably uniform
    int f = tid & 63;
    int i0 = blockIdx.x * 8;

    // zero the 2 MiB mask: 512 blocks x 512 threads x 1 uint2 = 2 MiB
    ((uint2*)mask)[blockIdx.x * 512 + tid] = make_uint2(0u, 0u);

    float acc[8];
#pragma unroll
    for (int r = 0; r < 8; ++r) acc[r] = 0.f;

    const float* Wp = W1 + (size_t)(w * 64) * HID + f;       // per-lane column base
    const float* xbase = x + (size_t)i0 * IN_F + w * 64;     // uniform base for this wave

    for (int k = 0; k < 64; k += 4) {
        float w0 = Wp[(k + 0) * HID];
        float w1_ = Wp[(k + 1) * HID];
        float w2 = Wp[(k + 2) * HID];
        float w3 = Wp[(k + 3) * HID];
#pragma unroll
        for (int r = 0; r < 8; ++r) {
            const float* xr = xbase + (size_t)r * IN_F + k;  // uniform -> s_load_dwordx4
            float x0 = xr[0], x1 = xr[1], x2 = xr[2], x3 = xr[3];
            acc[r] += x0 * w0 + x1 * w1_ + x2 * w2 + x3 * w3;
        }
    }
#pragma unroll
    for (int r = 0; r < 8; ++r) part[w][r][f] = acc[r];
    __syncthreads();

    // reduce the 8 K-slices: 512 outputs, one per thread
    {
        int r = tid >> 6, ff = tid & 63;
        float v = 0.f;
#pragma unroll
        for (int p = 0; p < 8; ++p) v += part[p][r][ff];
        h1[(size_t)(i0 + r) * HID + ff] = v;
        hs[r][ff] = v;
    }
    __syncthreads();

    // es/ed: thread t<64 handles (row r = t>>3, head h = t&7); F1 = 8
    if (tid < 64) {
        int r = tid >> 3, h = tid & 7;
        float s1 = 0.f, s2 = 0.f;
#pragma unroll
        for (int ff = 0; ff < 8; ++ff) {
            float hv = hs[r][h * 8 + ff];
            s1 += hv * a_src[h * 8 + ff];
            s2 += hv * a_dst[h * 8 + ff];
        }
        es[h * NNODES + (i0 + r)] = s1;
        ed[h * NNODES + (i0 + r)] = s2;
    }
}

// ---------------- layer 1 attention + fused layer-2 GEMM ----------------
// 1 block per node, 512 threads = 8 waves = 8 heads.
// Wave 0 builds the neighbor list by ballot/prefix compaction (no atomics).
// Softmax without max-shift: scores are bounded (|v| <~ 2), exp(v) safe in fp32,
// and softmax is shift-invariant -> identical result, no online rescale needed.
// Epilogue computes h2 = elu(hout) @ W2 and es2/ed2 (layer-2 gemm fused).
__global__ void __launch_bounds__(512) attn1_fused(const uint32_t* __restrict__ mask,
    const float* __restrict__ h1, const float* __restrict__ es, const float* __restrict__ ed,
    const float* __restrict__ W2, const float* __restrict__ a2s, const float* __restrict__ a2d,
    float* __restrict__ h2, float* __restrict__ es2, float* __restrict__ ed2) {
    __shared__ int nbr[CAP];
    __shared__ float hs[HID];            // elu'd hout row
    __shared__ float part[4][OUTF];
    __shared__ int degs;
    int i = blockIdx.x;
    int tid = threadIdx.x;
    int h = tid >> 6, lane = tid & 63;

    // wave 0: atomic-free neighbor compaction (2 mask words per lane)
    if (tid < 64) {
        uint32_t b0 = mask[(size_t)i * MASKW + 2 * tid];
        uint32_t b1 = mask[(size_t)i * MASKW + 2 * tid + 1];
        int cnt = __popc(b0) + __popc(b1);
        int incl = cnt;
#pragma unroll
        for (int d = 1; d < 64; d <<= 1) {
            int t = __shfl_up(incl, d, 64);
            if (tid >= d) incl += t;
        }
        int pos = incl - cnt;
        int base = tid * 64;
        while (b0) { int b = __ffs(b0) - 1; b0 &= b0 - 1; if (pos < CAP) nbr[pos] = base + b; ++pos; }
        base += 32;
        while (b1) { int b = __ffs(b1) - 1; b1 &= b1 - 1; if (pos < CAP) nbr[pos] = base + b; ++pos; }
        if (tid == 63) degs = (incl < CAP) ? incl : CAP;
    }
    __syncthreads();
    int n = degs;

    float es_i = es[h * NNODES + i];
    const float* edh = ed + h * NNODES;
    float s = 0.f;
    float acc[8];
#pragma unroll
    for (int f = 0; f < 8; ++f) acc[f] = 0.f;
    for (int t = lane; t < n; t += 64) {
        int j = nbr[t];
        float v = es_i + edh[j];
        v = v > 0.f ? v : 0.2f * v;          // leaky_relu slope 0.2
        float p = __expf(v);
        s += p;
        const float4* hj = (const float4*)(h1 + (size_t)j * HID + h * 8);
        float4 h0 = hj[0], h1v = hj[1];
        acc[0] += p * h0.x;  acc[1] += p * h0.y;
        acc[2] += p * h0.z;  acc[3] += p * h0.w;
        acc[4] += p * h1v.x; acc[5] += p * h1v.y;
        acc[6] += p * h1v.z; acc[7] += p * h1v.w;
    }
    // butterfly sum of (s, acc[8]) across the 64-lane wave
#pragma unroll
    for (int off = 32; off >= 1; off >>= 1) {
        s += __shfl_xor(s, off, 64);
#pragma unroll
        for (int f = 0; f < 8; ++f) acc[f] += __shfl_xor(acc[f], off, 64);
    }
    if (lane == 0) {
        float inv = (s > 0.f) ? 1.f / s : 0.f;
#pragma unroll
        for (int f = 0; f < 8; ++f) {
            float o = acc[f] * inv;
            o = o > 0.f ? o : (__expf(o) - 1.f);   // ELU fused
            hs[h * 8 + f] = o;
        }
    }
    __syncthreads();

    // fused layer-2 GEMM: h2[i] = hs @ W2  (64x16), split over 4 k-quarters
    if (tid < 64) {
        int q = tid >> 4, f = tid & 15;
        float p = 0.f;
#pragma unroll
        for (int k = 16 * q; k < 16 * q + 16; ++k) p += hs[k] * W2[k * OUTF + f];
        part[q][f] = p;
    }
    __syncthreads();
    if (tid < OUTF) {
        float v = part[0][tid] + part[1][tid] + part[2][tid] + part[3][tid];
        h2[(size_t)i * OUTF + tid] = v;
        hs[tid] = v;
    }
    __syncthreads();
    if (tid == 0) {
        float s1 = 0.f, s2 = 0.f;
#pragma unroll
        for (int f = 0; f < OUTF; ++f) { s1 += hs[f] * a2s[f]; s2 += hs[f] * a2d[f]; }
        es2[i] = s1;
        ed2[i] = s2;
    }
}

// ---------------- layer 2 attention + mean(1 head) + log_softmax ----------------
// block = 256 threads = 4 waves; wave w handles node blockIdx*4+w with its own LDS list
__global__ void __launch_bounds__(256) attn2(const uint32_t* __restrict__ mask,
    const float* __restrict__ h2, const float* __restrict__ es, const float* __restrict__ ed,
    float* __restrict__ out) {
    __shared__ int nbr[4][CAP];
    int tid = threadIdx.x;
    int wid = tid >> 6, lane = tid & 63;
    int i = blockIdx.x * 4 + wid;

    uint32_t b0 = mask[(size_t)i * MASKW + 2 * lane];
    uint32_t b1 = mask[(size_t)i * MASKW + 2 * lane + 1];
    int cnt = __popc(b0) + __popc(b1);
    int incl = cnt;
#pragma unroll
    for (int d = 1; d < 64; d <<= 1) {
        int t = __shfl_up(incl, d, 64);
        if (lane >= d) incl += t;
    }
    int pos = incl - cnt;
    int base = lane * 64;
    int* myn = &nbr[wid][0];
    while (b0) { int b = __ffs(b0) - 1; b0 &= b0 - 1; if (pos < CAP) myn[pos] = base + b; ++pos; }
    base += 32;
    while (b1) { int b = __ffs(b1) - 1; b1 &= b1 - 1; if (pos < CAP) myn[pos] = base + b; ++pos; }
    int n = __shfl(incl, 63, 64);
    n = n < CAP ? n : CAP;
    __syncthreads();   // cross-lane LDS visibility (all 4 waves pass once)

    float es_i = es[i];
    float s = 0.f;
    float acc[OUTF];
#pragma unroll
    for (int f = 0; f < OUTF; ++f) acc[f] = 0.f;
    for (int t = lane; t < n; t += 64) {
        int j = myn[t];
        float v = es_i + ed[j];
        v = v > 0.f ? v : 0.2f * v;
        float p = __expf(v);
        s += p;
        const float4* hj = (const float4*)(h2 + (size_t)j * OUTF);
        float4 q0 = hj[0], q1 = hj[1], q2 = hj[2], q3 = hj[3];
        acc[0]  += p * q0.x; acc[1]  += p * q0.y;
        acc[2]  += p * q0.z; acc[3]  += p * q0.w;
        acc[4]  += p * q1.x; acc[5]  += p * q1.y;
        acc[6]  += p * q1.z; acc[7]  += p * q1.w;
        acc[8]  += p * q2.x; acc[9]  += p * q2.y;
        acc[10] += p * q2.z; acc[11] += p * q2.w;
        acc[12] += p * q3.x; acc[13] += p * q3.y;
        acc[14] += p * q3.z; acc[15] += p * q3.w;
    }
#pragma unroll
    for (int off = 32; off >= 1; off >>= 1) {
        s += __shfl_xor(s, off, 64);
#pragma unroll
        for (int f = 0; f < OUTF; ++f) acc[f] += __shfl_xor(acc[f], off, 64);
    }
    if (lane == 0) {
        float inv = (s > 0.f) ? 1.f / s : 0.f;
        float v[OUTF];
        float mx = -1e30f;
#pragma unroll
        for (int f = 0; f < OUTF; ++f) {
            v[f] = acc[f] * inv;
            mx = fmaxf(mx, v[f]);
        }
        float se = 0.f;
#pragma unroll
        for (int f = 0; f < OUTF; ++f) se += __expf(v[f] - mx);
        float lse = mx + __logf(se);
#pragma unroll
        for (int f = 0; f < OUTF; ++f)
            out[(size_t)i * OUTF + f] = v[f] - lse;
    }
}

extern "C" void kernel_launch(void* const* d_in, const int* in_sizes, int n_in,
                              void* d_out, int out_size, void* d_ws, size_t ws_size,
                              hipStream_t stream) {
    const float* x   = (const float*)d_in[0];
    const int*   ei  = (const int*)d_in[1];
    const float* W1  = (const float*)d_in[2];
    const float* a1s = (const float*)d_in[3];
    const float* a1d = (const float*)d_in[4];
    const float* W2  = (const float*)d_in[5];
    const float* a2s = (const float*)d_in[6];
    const float* a2d = (const float*)d_in[7];
    float* out = (float*)d_out;
    int E = in_sizes[1] / 2;

    char* ws = (char*)d_ws;
    uint32_t* mask = (uint32_t*)ws;                // 2 MiB
    float* h1   = (float*)(ws + 2097152);          // 1 MiB   [N][64]
    float* es1  = (float*)(ws + 3145728);          // 128 KiB [8][N]
    float* ed1  = (float*)(ws + 3276800);          // 128 KiB [8][N]
    float* h2   = (float*)(ws + 3407872);          // 256 KiB [N][16]
    float* es2  = (float*)(ws + 3670016);          // 16 KiB  [N]
    float* ed2  = (float*)(ws + 3686400);          // 16 KiB  [N]

    // gemm1 zeroes mask (it precedes scatter_edges in stream order)
    gemm1<<<NNODES / 8, 512, 0, stream>>>(x, W1, a1s, a1d, h1, es1, ed1, mask);
    scatter_edges<<<(E + 255) / 256, 256, 0, stream>>>(ei, E, mask);
    attn1_fused<<<NNODES, 512, 0, stream>>>(mask, h1, es1, ed1, W2, a2s, a2d, h2, es2, ed2);
    attn2<<<NNODES / 4, 256, 0, stream>>>(mask, h2, es2, ed2, out);
}